// Round 16
// baseline (756.761 us; speedup 1.0000x reference)
//
#include <hip/hip_runtime.h>

// ---------------------------------------------------------------------------
// Encoder_18365280157999: GCN-VGAE encoder on MI355X (gfx950).
//   h0 = relu(x @ w_dense + b);  A1 = Agg(h0);  h1 = A1 @ w_enc + b
//   A2 = Agg(h1);  mu = A2 @ w_mu + b;  logstd = A2 @ w_logstd + b
//
// R11 (5th submit; four consecutive GPU acquisition timeouts, never measured):
//  * gemm_pack pack-branch unroll x4: 4 independent u64 atomics in flight per
//    thread before rank stores. R10 measured Occ 29.9% (48KB LDS cap -> 12
//    waves/CU, half of standalone edge_pack) and gemm_pack 133 us ~= serial
//    sum -> atomic phase was MLP-starved. 4x queue depth at same occupancy.
//  * init_kernel -> hipMemsetAsync (acc zeroing); dinv folded into scanA
//    (already loads acc[i]). Two launches removed.
// R10: grid-fused GEMM-1 + edge_pack (764.4 -> 748.9); R9 column-split spmm
//      reverted (request-rate-bound, not L2-capacity-sensitive).
// R8: GEMM double-buffered 2-phase (832.6 -> 764.4).
// R6: 1 u64 atomic/edge (count hi / fixpt weight-sum lo), rank from atomic
//     return -> atomic-free CSR fill.
//
// SpMM floor note: 409 MB L2-miss traffic @ ~4 TB/s, request-rate bound
// (R7/R9 falsifiers both triggered); ~126 us/aggregation floor as formulated.
//
// Fragment-major addressing for element (row r, col k) of an [n x 256] bf16:
//   T=r>>4, l=r&15, K=k>>5, q=(k>>3)&3, j=k&7
//   short offset = (T*8+K)*512 + q*128 + l*8 + j       (chunk = 1KB)
// ---------------------------------------------------------------------------

typedef short bf16x8 __attribute__((ext_vector_type(8)));
typedef float f32x4 __attribute__((ext_vector_type(4)));

static __device__ __forceinline__ unsigned int f2bf(float f) {
    unsigned int u = __float_as_uint(f);
    return ((u + 0x7fffu + ((u >> 16) & 1u)) >> 16) & 0xffffu;  // RNE
}
static __device__ __forceinline__ float bf2f(unsigned int us) {
    return __uint_as_float(us << 16);
}

static __device__ __forceinline__ void load_lds16(const void* g, void* l) {
    __builtin_amdgcn_global_load_lds(
        (const __attribute__((address_space(1))) unsigned int*)g,
        (__attribute__((address_space(3))) unsigned int*)l, 16, 0, 0);
}

#define FIXSCALE 8388608.0f  // 2^23; max safe weighted degree ~512

// ---------------- preprocessing ----------------

// Hierarchical scan, stage A (+ dinv fused): per-block (1024) local exclusive
// scan of counts (hi words of acc) + block sum; also writes dinv from lo words.
__global__ __launch_bounds__(1024) void scanA_kernel(const unsigned long long* __restrict__ acc,
                                                     int* __restrict__ offsets,
                                                     int* __restrict__ bsum,
                                                     float* __restrict__ dinv, int n) {
    __shared__ int wsum[16];
    int tid = threadIdx.x, lane = tid & 63, wv = tid >> 6;
    int i = blockIdx.x * 1024 + tid;
    unsigned long long a = (i < n) ? acc[i] : 0ull;
    if (i < n) {
        float deg = 1.0f + (float)(unsigned int)a * (1.0f / FIXSCALE);  // self-loop +1
        dinv[i] = rsqrtf(deg);
    }
    int v = (int)(a >> 32);
    int s = v;
#pragma unroll
    for (int off = 1; off < 64; off <<= 1) {
        int t = __shfl_up(s, off, 64);
        if (lane >= off) s += t;
    }
    if (lane == 63) wsum[wv] = s;
    __syncthreads();
    if (wv == 0 && lane < 16) {
        int w = wsum[lane];
        int ss = w;
#pragma unroll
        for (int off = 1; off < 16; off <<= 1) {
            int t = __shfl_up(ss, off, 64);
            if (lane >= off) ss += t;
        }
        wsum[lane] = ss - w;
        if (lane == 15) bsum[blockIdx.x] = ss;
    }
    __syncthreads();
    if (i < n) offsets[i] = wsum[wv] + s - v;
}

// Stage B: scan the <=128 block sums in one block; write offsets[n]=total.
__global__ __launch_bounds__(128) void scanB_kernel(int* __restrict__ bsum, int nb,
                                                    int* __restrict__ offsets, int n) {
    __shared__ int w0tot;
    int tid = threadIdx.x, lane = tid & 63, wv = tid >> 6;
    int v = (tid < nb) ? bsum[tid] : 0;
    int s = v;
#pragma unroll
    for (int off = 1; off < 64; off <<= 1) {
        int t = __shfl_up(s, off, 64);
        if (lane >= off) s += t;
    }
    if (wv == 0 && lane == 63) w0tot = s;
    __syncthreads();
    int excl = s - v + (wv ? w0tot : 0);
    if (tid < nb) bsum[tid] = excl;
    if (tid == nb - 1) offsets[n] = excl + v;
}

// Stage C: add block prefixes.
__global__ __launch_bounds__(256) void scanC_kernel(int* __restrict__ offsets,
                                                    const int* __restrict__ bsum, int n) {
    int i = blockIdx.x * 256 + threadIdx.x;
    if (i < n) offsets[i] += bsum[i >> 10];
}

// Fill CSR without atomics: pos = offsets[c] + rank[e].
__global__ __launch_bounds__(256) void fill2_kernel(const int* __restrict__ row,
                                                    const int* __restrict__ col,
                                                    const float* __restrict__ ew,
                                                    const unsigned int* __restrict__ rank,
                                                    const int* __restrict__ offsets,
                                                    const float* __restrict__ dinv,
                                                    uint2* __restrict__ edges, int E) {
    int e = blockIdx.x * 256 + threadIdx.x;
    if (e < E) {
        int c = col[e];
        int r = row[e];
        int pos = offsets[c] + (int)rank[e];
        uint2 p;
        p.x = (unsigned int)r;
        p.y = __float_as_uint(dinv[r] * ew[e]);
        edges[pos] = p;
    }
}

// x (fp32 row-major) -> bf16 fragment-major. One wave per row; lane covers 4 k.
__global__ __launch_bounds__(256) void cvt_frag_kernel(const float* __restrict__ x,
                                                       unsigned short* __restrict__ Af, int n) {
    int g = blockIdx.x * 256 + threadIdx.x;
    int c = g >> 6, lane = g & 63;
    if (c >= n) return;
    float4 v = ((const float4*)x)[(size_t)c * 64 + lane];
    uint2 w;
    w.x = f2bf(v.x) | (f2bf(v.y) << 16);
    w.y = f2bf(v.z) | (f2bf(v.w) << 16);
    int T = c >> 4, l = c & 15;
    size_t idx8 = (size_t)T * 1024 + (size_t)((lane >> 3)) * 128 + ((lane >> 1) & 3) * 32 + l * 2 + (lane & 1);
    ((uint2*)Af)[idx8] = w;
}

// W [256 x M] fp32 -> fragment-major split Wh/Wl [Tc][K][q][l][j] bf16.
__global__ __launch_bounds__(256) void splitw_kernel(const float* __restrict__ W, int M,
                                                     unsigned short* __restrict__ hi,
                                                     unsigned short* __restrict__ lo) {
    int idx = blockIdx.x * 256 + threadIdx.x;  // idx = c*256 + k
    if (idx < M * 256) {
        int c = idx >> 8, k = idx & 255;
        float w = W[k * M + c];
        unsigned int h = f2bf(w);
        float r = w - bf2f(h);
        int T = c >> 4, l = c & 15, K = k >> 5, q = (k >> 3) & 3, j = k & 7;
        size_t o = (size_t)(T * 8 + K) * 512 + q * 128 + l * 8 + j;
        hi[o] = (unsigned short)h;
        lo[o] = (unsigned short)f2bf(r);
    }
}

// Concatenate two 128-float biases into one 256-float buffer.
__global__ __launch_bounds__(256) void bcat_kernel(const float* __restrict__ a,
                                                   const float* __restrict__ b,
                                                   float* __restrict__ o) {
    int t = threadIdx.x;
    o[t] = (t < 128) ? a[t] : b[t - 128];
}

// ---------------- SpMM (bf16 gather, row-major in, fragment-major out) ------
// One wave per destination node. Lanes 0-31 (half 0) and 32-63 (half 1) each
// own one edge of a pair; each lane gathers 16B (8 cols). Self-loop + odd tail
// folded into one predicated final iteration. Cross-half shfl_xor reduce.
#define ACC8(qv, uv)                                      \
    do {                                                  \
        float w_ = __uint_as_float((qv).y);               \
        a0 += w_ * __uint_as_float((uv).x << 16);         \
        a1 += w_ * __uint_as_float((uv).x & 0xffff0000u); \
        a2 += w_ * __uint_as_float((uv).y << 16);         \
        a3 += w_ * __uint_as_float((uv).y & 0xffff0000u); \
        a4 += w_ * __uint_as_float((uv).z << 16);         \
        a5 += w_ * __uint_as_float((uv).z & 0xffff0000u); \
        a6 += w_ * __uint_as_float((uv).w << 16);         \
        a7 += w_ * __uint_as_float((uv).w & 0xffff0000u); \
    } while (0)

__global__ __launch_bounds__(256) void spmm_kernel(const unsigned short* __restrict__ h,
                                                   const uint2* __restrict__ edges,
                                                   const int* __restrict__ offsets,
                                                   const float* __restrict__ dinv,
                                                   unsigned short* __restrict__ outf, int n) {
    int wave = threadIdx.x >> 6;
    int lane = threadIdx.x & 63;
    int half = lane >> 5, hl = lane & 31;
    int c = blockIdx.x * 4 + wave;
    if (c >= n) return;
    const uint4* __restrict__ h4 = (const uint4*)h;
    float di = dinv[c];
    int beg = __builtin_amdgcn_readfirstlane(offsets[c]);
    int end = __builtin_amdgcn_readfirstlane(offsets[c + 1]);
    int d = end - beg;
    int elim = beg + (d & ~1);

    float a0 = 0.f, a1 = 0.f, a2 = 0.f, a3 = 0.f;
    float a4 = 0.f, a5 = 0.f, a6 = 0.f, a7 = 0.f;

    int e = beg;
    for (; e + 8 <= elim; e += 8) {
        uint2 q0 = edges[e + 0 + half];
        uint2 q1 = edges[e + 2 + half];
        uint2 q2 = edges[e + 4 + half];
        uint2 q3 = edges[e + 6 + half];
        uint4 u0 = h4[(size_t)q0.x * 32 + hl];
        uint4 u1 = h4[(size_t)q1.x * 32 + hl];
        uint4 u2 = h4[(size_t)q2.x * 32 + hl];
        uint4 u3 = h4[(size_t)q3.x * 32 + hl];
        ACC8(q0, u0);
        ACC8(q1, u1);
        ACC8(q2, u2);
        ACC8(q3, u3);
    }
    for (; e < elim; e += 2) {
        uint2 q = edges[e + half];
        uint4 u = h4[(size_t)q.x * 32 + hl];
        ACC8(q, u);
    }
    // Final iteration: half 0 processes the self-loop (weight dinv[c]; the
    // trailing *di below makes it dinv^2 as required); half 1 processes the
    // odd tail edge if present, else contributes weight 0.
    {
        uint2 qf;
        qf.x = (unsigned int)c;
        qf.y = half ? 0u : __float_as_uint(di);
        if (half && (d & 1)) qf = edges[end - 1];
        uint4 uf = h4[(size_t)qf.x * 32 + hl];
        ACC8(qf, uf);
    }

    // combine halves (both halves cover the same 8 columns)
    a0 += __shfl_xor(a0, 32);
    a1 += __shfl_xor(a1, 32);
    a2 += __shfl_xor(a2, 32);
    a3 += __shfl_xor(a3, 32);
    a4 += __shfl_xor(a4, 32);
    a5 += __shfl_xor(a5, 32);
    a6 += __shfl_xor(a6, 32);
    a7 += __shfl_xor(a7, 32);

    if (half == 0) {
        uint4 wv;
        wv.x = f2bf(di * a0) | (f2bf(di * a1) << 16);
        wv.y = f2bf(di * a2) | (f2bf(di * a3) << 16);
        wv.z = f2bf(di * a4) | (f2bf(di * a5) << 16);
        wv.w = f2bf(di * a6) | (f2bf(di * a7) << 16);
        int T = c >> 4, l = c & 15;
        // lane hl covers cols 8*hl..8*hl+7: K=hl>>2, q=hl&3, j=0..7 contiguous
        size_t o16 = ((size_t)T * 8 + (hl >> 2)) * 512 + (size_t)(hl & 3) * 128 + (size_t)l * 8;
        *(uint4*)(outf + o16) = wv;
    }
}

// ---------------- GEMM body (double-buffered 2-phase), shared by both -------
// flags: 1 = relu, 2 = bf16 output, 4 = dual fp32 output.
static __device__ __forceinline__ void gemm_body(const unsigned short* __restrict__ Af,
                                                 const unsigned short* __restrict__ Wh,
                                                 const unsigned short* __restrict__ Wl,
                                                 const float* __restrict__ bias,
                                                 void* __restrict__ outp,
                                                 int n, int M, int flags,
                                                 int bx, int by, short* lds /*[2][12288]*/) {
    int tid = threadIdx.x, lane = tid & 63, wave = tid >> 6;
    int wr = wave & 1, wc = wave >> 1;
    int l16 = lane & 15, quad = lane >> 4;
    int T0 = bx * 8;   // A tile base (rows /16)
    int Tc0 = by * 8;  // B tile base (cols /16)

    f32x4 acc[4][4];
#pragma unroll
    for (int i = 0; i < 4; ++i)
#pragma unroll
        for (int j = 0; j < 4; ++j) acc[i][j] = (f32x4)0.0f;

    auto stage = [&](int b, int K) {
#pragma unroll
        for (int j = 0; j < 6; ++j) {
            int cid = wave * 6 + j;
            const unsigned short* g;
            if (cid < 8)       g = Af + ((size_t)(T0 + cid) * 8 + K) * 512;
            else if (cid < 16) g = Wh + ((size_t)(Tc0 + cid - 8) * 8 + K) * 512;
            else               g = Wl + ((size_t)(Tc0 + cid - 16) * 8 + K) * 512;
            load_lds16(g + (size_t)lane * 8, lds + b * 12288 + cid * 512);
        }
    };

    stage(0, 0);
    __syncthreads();  // drains vmcnt(0) + barrier: buf0 ready

    for (int K = 0; K < 8; ++K) {
        int cur = K & 1;
        if (K < 7) stage(cur ^ 1, K + 1);  // in flight during compute below
        bf16x8 af[4], bh[4], bl[4];
#pragma unroll
        for (int t = 0; t < 4; ++t) {
            af[t] = *(const bf16x8*)(lds + cur * 12288 + (4 * wr + t) * 512 + lane * 8);
            bh[t] = *(const bf16x8*)(lds + cur * 12288 + 4096 + (4 * wc + t) * 512 + lane * 8);
            bl[t] = *(const bf16x8*)(lds + cur * 12288 + 8192 + (4 * wc + t) * 512 + lane * 8);
        }
#pragma unroll
        for (int rt = 0; rt < 4; ++rt)
#pragma unroll
            for (int ct = 0; ct < 4; ++ct) {
                acc[rt][ct] = __builtin_amdgcn_mfma_f32_16x16x32_bf16(af[rt], bh[ct], acc[rt][ct], 0, 0, 0);
                acc[rt][ct] = __builtin_amdgcn_mfma_f32_16x16x32_bf16(af[rt], bl[ct], acc[rt][ct], 0, 0, 0);
            }
        if (K < 7) __syncthreads();  // drains next-stage vmcnt; buf swap safe
    }

    int relu = flags & 1, obf = flags & 2, dual = flags & 4;
    int r0 = T0 * 16, c0 = Tc0 * 16;
#pragma unroll
    for (int ct = 0; ct < 4; ++ct) {
        int col = c0 + 64 * wc + 16 * ct + l16;
        float b = bias[col];
#pragma unroll
        for (int rt = 0; rt < 4; ++rt) {
            int rbase = r0 + 64 * wr + 16 * rt + quad * 4;
#pragma unroll
            for (int i = 0; i < 4; ++i) {
                int r = rbase + i;
                if (r < n) {
                    float v = acc[rt][ct][i] + b;
                    if (relu) v = fmaxf(v, 0.0f);
                    if (dual)
                        ((float*)outp)[(size_t)(col >> 7) * ((size_t)n * 128) + (size_t)r * 128 + (col & 127)] = v;
                    else if (obf)
                        ((unsigned short*)outp)[(size_t)r * M + col] = (unsigned short)f2bf(v);
                    else
                        ((float*)outp)[(size_t)r * M + col] = v;
                }
            }
        }
    }
}

// Standalone GEMM (GEMM-2 enc, GEMM-3 dual).
__global__ __launch_bounds__(256) void mfma_gemm_kernel(const unsigned short* __restrict__ Af,
                                                        const unsigned short* __restrict__ Wh,
                                                        const unsigned short* __restrict__ Wl,
                                                        const float* __restrict__ bias,
                                                        void* __restrict__ outp,
                                                        int n, int M, int flags) {
    __shared__ short lds[2 * 12288];
    gemm_body(Af, Wh, Wl, bias, outp, n, M, flags, blockIdx.x, blockIdx.y, lds);
}

// Fused GEMM-1 + edge_pack: blocks [0, nGemm) run the dense GEMM (flattened
// bx = b % nTile, by = b / nTile); blocks [nGemm, ...) run edge_pack with
// 4 edges per thread (1024 per block): 4 independent u64 atomics in flight
// per lane compensates the 12-waves/CU occupancy cap from the 48KB LDS.
__global__ __launch_bounds__(256) void gemm_pack_kernel(const unsigned short* __restrict__ Af,
                                                        const unsigned short* __restrict__ Wh,
                                                        const unsigned short* __restrict__ Wl,
                                                        const float* __restrict__ bias,
                                                        void* __restrict__ outp,
                                                        int n, int M, int flags,
                                                        int nGemm, int nTile,
                                                        const int* __restrict__ col,
                                                        const float* __restrict__ ew,
                                                        unsigned long long* __restrict__ acc,
                                                        unsigned int* __restrict__ rank, int E) {
    __shared__ short lds[2 * 12288];
    int b = blockIdx.x;
    if (b < nGemm) {
        gemm_body(Af, Wh, Wl, bias, outp, n, M, flags, b % nTile, b / nTile, lds);
    } else {
        int base = (b - nGemm) * 1024 + threadIdx.x;
        int e0 = base, e1 = base + 256, e2 = base + 512, e3 = base + 768;
        // Issue all valid atomics back-to-back (independent; vmcnt queues them),
        // then store ranks.
        unsigned long long o0 = 0, o1 = 0, o2 = 0, o3 = 0;
        if (e0 < E) {
            unsigned long long pk = (1ull << 32) |
                                    (unsigned long long)(unsigned int)(ew[e0] * FIXSCALE + 0.5f);
            o0 = atomicAdd(&acc[col[e0]], pk);
        }
        if (e1 < E) {
            unsigned long long pk = (1ull << 32) |
                                    (unsigned long long)(unsigned int)(ew[e1] * FIXSCALE + 0.5f);
            o1 = atomicAdd(&acc[col[e1]], pk);
        }
        if (e2 < E) {
            unsigned long long pk = (1ull << 32) |
                                    (unsigned long long)(unsigned int)(ew[e2] * FIXSCALE + 0.5f);
            o2 = atomicAdd(&acc[col[e2]], pk);
        }
        if (e3 < E) {
            unsigned long long pk = (1ull << 32) |
                                    (unsigned long long)(unsigned int)(ew[e3] * FIXSCALE + 0.5f);
            o3 = atomicAdd(&acc[col[e3]], pk);
        }
        if (e0 < E) rank[e0] = (unsigned int)(o0 >> 32);
        if (e1 < E) rank[e1] = (unsigned int)(o1 >> 32);
        if (e2 < E) rank[e2] = (unsigned int)(o2 >> 32);
        if (e3 < E) rank[e3] = (unsigned int)(o3 >> 32);
    }
}

// ---------------- launch ----------------

extern "C" void kernel_launch(void* const* d_in, const int* in_sizes, int n_in,
                              void* d_out, int out_size, void* d_ws, size_t ws_size,
                              hipStream_t stream) {
    const float* x        = (const float*)d_in[0];
    const int*   ei       = (const int*)d_in[1];   // int32 (harness converts)
    const float* ea       = (const float*)d_in[2];
    const float* w_dense  = (const float*)d_in[3];
    const float* b_dense  = (const float*)d_in[4];
    const float* w_enc    = (const float*)d_in[5];
    const float* b_enc    = (const float*)d_in[6];
    const float* w_mu     = (const float*)d_in[7];
    const float* b_mu     = (const float*)d_in[8];
    const float* w_logstd = (const float*)d_in[9];
    const float* b_logstd = (const float*)d_in[10];

    const int n = in_sizes[0] / 256;  // 100000 (divisible by 16)
    const int E = in_sizes[2];        // 1600000
    const int* row = ei;
    const int* col = ei + E;

    char* ws = (char*)d_ws;
    size_t off = 0;
    auto alloc = [&](size_t bytes) -> void* {
        void* p = ws + off;
        off = (off + bytes + 255) & ~(size_t)255;
        return p;
    };
    const int nTile = (n + 127) / 128;        // 782 row-blocks
    const int nTpad = nTile * 8;              // 6256 T-chunks (pad: garbage ok, never stored)
    unsigned long long* acc = (unsigned long long*)alloc((size_t)n * 8);
    float* dinv   = (float*)alloc((size_t)n * 4);
    int*   offs   = (int*)alloc((size_t)(n + 1) * 4);
    int*   bsum   = (int*)alloc(128 * 4);
    unsigned int* rank = (unsigned int*)alloc((size_t)E * 4);
    uint2* edges  = (uint2*)alloc((size_t)E * 8);
    unsigned short* Af   = (unsigned short*)alloc((size_t)nTpad * 8192);  // frag activations
    unsigned short* wd_h = (unsigned short*)alloc(256 * 256 * 2);
    unsigned short* wd_l = (unsigned short*)alloc(256 * 256 * 2);
    unsigned short* we_h = (unsigned short*)alloc(256 * 256 * 2);
    unsigned short* we_l = (unsigned short*)alloc(256 * 256 * 2);
    unsigned short* wf_h = (unsigned short*)alloc(256 * 256 * 2);  // mu|logstd concat
    unsigned short* wf_l = (unsigned short*)alloc(256 * 256 * 2);
    float*          bcat = (float*)alloc(256 * 4);
    (void)ws_size;

    // d_out doubles as row-major activation storage (dead before final writes)
    unsigned short* h1b = (unsigned short*)d_out;                    // lower: h1, then mu
    unsigned short* h0b = (unsigned short*)d_out + (size_t)n * 256;  // upper: h0, then logstd

    int nb_n = (n + 255) / 256;
    int nb_e = (E + 255) / 256;
    int nb_p = (E + 1023) / 1024;  // pack blocks (4 edges/thread)
    int nb_s = (n + 1023) / 1024;  // 98 scan blocks
    int nGemm = nTile * 2;         // 1564 GEMM blocks in the fused dispatch

    // prep (independent of edges)
    hipMemsetAsync(acc, 0, (size_t)n * 8, stream);
    cvt_frag_kernel<<<(n * 64 + 255) / 256, 256, 0, stream>>>(x, Af, n);
    splitw_kernel<<<256, 256, 0, stream>>>(w_dense, 256, wd_h, wd_l);
    splitw_kernel<<<256, 256, 0, stream>>>(w_enc, 256, we_h, we_l);
    splitw_kernel<<<128, 256, 0, stream>>>(w_mu, 128, wf_h, wf_l);
    splitw_kernel<<<128, 256, 0, stream>>>(w_logstd, 128, wf_h + 32768, wf_l + 32768);
    bcat_kernel<<<1, 256, 0, stream>>>(b_mu, b_logstd, bcat);

    // fused: GEMM-1 (dense+relu, bf16 out) overlapped with edge_pack atomics
    gemm_pack_kernel<<<nGemm + nb_p, 256, 0, stream>>>(Af, wd_h, wd_l, b_dense, h0b,
                                                       n, 256, 1 | 2, nGemm, nTile,
                                                       col, ea, acc, rank, E);

    // rest of graph preprocessing (dinv fused into scanA)
    scanA_kernel<<<nb_s, 1024, 0, stream>>>(acc, offs, bsum, dinv, n);
    scanB_kernel<<<1, 128, 0, stream>>>(bsum, nb_s, offs, n);
    scanC_kernel<<<nb_n, 256, 0, stream>>>(offs, bsum, n);
    fill2_kernel<<<nb_e, 256, 0, stream>>>(row, col, ea, rank, offs, dinv, edges, E);

    // pipeline
    spmm_kernel<<<(n + 3) / 4, 256, 0, stream>>>(h0b, edges, offs, dinv, Af, n);
    mfma_gemm_kernel<<<dim3(nTile, 2), 256, 0, stream>>>(Af, we_h, we_l, b_enc, h1b, n, 256, 2);
    spmm_kernel<<<(n + 3) / 4, 256, 0, stream>>>(h1b, edges, offs, dinv, Af, n);
    mfma_gemm_kernel<<<dim3(nTile, 2), 256, 0, stream>>>(Af, wf_h, wf_l, bcat, d_out, n, 128, 4);
}

// Round 17
// 746.094 us; speedup vs baseline: 1.0143x; 1.0143x over previous
//
#include <hip/hip_runtime.h>

// ---------------------------------------------------------------------------
// Encoder_18365280157999: GCN-VGAE encoder on MI355X (gfx950).
//   h0 = relu(x @ w_dense + b);  A1 = Agg(h0);  h1 = A1 @ w_enc + b
//   A2 = Agg(h1);  mu = A2 @ w_mu + b;  logstd = A2 @ w_logstd + b
//
// R12 (this round):
//  * Revert R11 pack unroll x4 (measured 133 -> 146 us: atomic path is
//    queue-depth-insensitive; line-migration serialization sets the rate).
//    Back to 1 edge/thread in the fused pack branch.
//  * scanC eliminated: consumers add the block prefix themselves.
//    fill2: pos = offsets[c] + bsum[c>>10] + rank[e];
//    spmm:  beg/end = offsets[c] + bsum[c>>10] (offsets[n] is global total).
//    bsum = 392B, L2-resident; removes an n-element RMW pass + launch.
//  * Kept from R11: hipMemsetAsync acc-init; dinv folded into scanA.
// R10: grid-fused GEMM-1 + edge_pack (764.4 -> 748.9, best measured); R9
//      column-split spmm reverted (request-rate-bound).
// R8: GEMM double-buffered 2-phase (832.6 -> 764.4).
// R6: 1 u64 atomic/edge (count hi / fixpt weight-sum lo), rank from atomic
//     return -> atomic-free CSR fill.
//
// SpMM floor note: 409 MB L2-miss traffic @ ~4 TB/s, request-rate bound
// (R7/R9 falsifiers both triggered); ~126 us/aggregation floor as formulated.
// Atomic floor note: edge_pack ~74.5 us standalone / ~76 us inside fusion
// window; per-line migration bound, insensitive to queue depth (R11).
//
// Fragment-major addressing for element (row r, col k) of an [n x 256] bf16:
//   T=r>>4, l=r&15, K=k>>5, q=(k>>3)&3, j=k&7
//   short offset = (T*8+K)*512 + q*128 + l*8 + j       (chunk = 1KB)
// ---------------------------------------------------------------------------

typedef short bf16x8 __attribute__((ext_vector_type(8)));
typedef float f32x4 __attribute__((ext_vector_type(4)));

static __device__ __forceinline__ unsigned int f2bf(float f) {
    unsigned int u = __float_as_uint(f);
    return ((u + 0x7fffu + ((u >> 16) & 1u)) >> 16) & 0xffffu;  // RNE
}
static __device__ __forceinline__ float bf2f(unsigned int us) {
    return __uint_as_float(us << 16);
}

static __device__ __forceinline__ void load_lds16(const void* g, void* l) {
    __builtin_amdgcn_global_load_lds(
        (const __attribute__((address_space(1))) unsigned int*)g,
        (__attribute__((address_space(3))) unsigned int*)l, 16, 0, 0);
}

#define FIXSCALE 8388608.0f  // 2^23; max safe weighted degree ~512

// ---------------- preprocessing ----------------

// Hierarchical scan, stage A (+ dinv fused): per-block (1024) local exclusive
// scan of counts (hi words of acc) + block sum; also writes dinv from lo words.
__global__ __launch_bounds__(1024) void scanA_kernel(const unsigned long long* __restrict__ acc,
                                                     int* __restrict__ offsets,
                                                     int* __restrict__ bsum,
                                                     float* __restrict__ dinv, int n) {
    __shared__ int wsum[16];
    int tid = threadIdx.x, lane = tid & 63, wv = tid >> 6;
    int i = blockIdx.x * 1024 + tid;
    unsigned long long a = (i < n) ? acc[i] : 0ull;
    if (i < n) {
        float deg = 1.0f + (float)(unsigned int)a * (1.0f / FIXSCALE);  // self-loop +1
        dinv[i] = rsqrtf(deg);
    }
    int v = (int)(a >> 32);
    int s = v;
#pragma unroll
    for (int off = 1; off < 64; off <<= 1) {
        int t = __shfl_up(s, off, 64);
        if (lane >= off) s += t;
    }
    if (lane == 63) wsum[wv] = s;
    __syncthreads();
    if (wv == 0 && lane < 16) {
        int w = wsum[lane];
        int ss = w;
#pragma unroll
        for (int off = 1; off < 16; off <<= 1) {
            int t = __shfl_up(ss, off, 64);
            if (lane >= off) ss += t;
        }
        wsum[lane] = ss - w;
        if (lane == 15) bsum[blockIdx.x] = ss;
    }
    __syncthreads();
    if (i < n) offsets[i] = wsum[wv] + s - v;  // block-local exclusive
}

// Stage B: scan the <=128 block sums in one block (bsum -> global exclusive
// block prefixes); write offsets[n] = global total.
__global__ __launch_bounds__(128) void scanB_kernel(int* __restrict__ bsum, int nb,
                                                    int* __restrict__ offsets, int n) {
    __shared__ int w0tot;
    int tid = threadIdx.x, lane = tid & 63, wv = tid >> 6;
    int v = (tid < nb) ? bsum[tid] : 0;
    int s = v;
#pragma unroll
    for (int off = 1; off < 64; off <<= 1) {
        int t = __shfl_up(s, off, 64);
        if (lane >= off) s += t;
    }
    if (wv == 0 && lane == 63) w0tot = s;
    __syncthreads();
    int excl = s - v + (wv ? w0tot : 0);
    if (tid < nb) bsum[tid] = excl;
    if (tid == nb - 1) offsets[n] = excl + v;
}

// Fill CSR without atomics: pos = offsets[c] + bsum[c>>10] + rank[e].
__global__ __launch_bounds__(256) void fill2_kernel(const int* __restrict__ row,
                                                    const int* __restrict__ col,
                                                    const float* __restrict__ ew,
                                                    const unsigned int* __restrict__ rank,
                                                    const int* __restrict__ offsets,
                                                    const int* __restrict__ bsum,
                                                    const float* __restrict__ dinv,
                                                    uint2* __restrict__ edges, int E) {
    int e = blockIdx.x * 256 + threadIdx.x;
    if (e < E) {
        int c = col[e];
        int r = row[e];
        int pos = offsets[c] + bsum[c >> 10] + (int)rank[e];
        uint2 p;
        p.x = (unsigned int)r;
        p.y = __float_as_uint(dinv[r] * ew[e]);
        edges[pos] = p;
    }
}

// x (fp32 row-major) -> bf16 fragment-major. One wave per row; lane covers 4 k.
__global__ __launch_bounds__(256) void cvt_frag_kernel(const float* __restrict__ x,
                                                       unsigned short* __restrict__ Af, int n) {
    int g = blockIdx.x * 256 + threadIdx.x;
    int c = g >> 6, lane = g & 63;
    if (c >= n) return;
    float4 v = ((const float4*)x)[(size_t)c * 64 + lane];
    uint2 w;
    w.x = f2bf(v.x) | (f2bf(v.y) << 16);
    w.y = f2bf(v.z) | (f2bf(v.w) << 16);
    int T = c >> 4, l = c & 15;
    size_t idx8 = (size_t)T * 1024 + (size_t)((lane >> 3)) * 128 + ((lane >> 1) & 3) * 32 + l * 2 + (lane & 1);
    ((uint2*)Af)[idx8] = w;
}

// W [256 x M] fp32 -> fragment-major split Wh/Wl [Tc][K][q][l][j] bf16.
__global__ __launch_bounds__(256) void splitw_kernel(const float* __restrict__ W, int M,
                                                     unsigned short* __restrict__ hi,
                                                     unsigned short* __restrict__ lo) {
    int idx = blockIdx.x * 256 + threadIdx.x;  // idx = c*256 + k
    if (idx < M * 256) {
        int c = idx >> 8, k = idx & 255;
        float w = W[k * M + c];
        unsigned int h = f2bf(w);
        float r = w - bf2f(h);
        int T = c >> 4, l = c & 15, K = k >> 5, q = (k >> 3) & 3, j = k & 7;
        size_t o = (size_t)(T * 8 + K) * 512 + q * 128 + l * 8 + j;
        hi[o] = (unsigned short)h;
        lo[o] = (unsigned short)f2bf(r);
    }
}

// Concatenate two 128-float biases into one 256-float buffer.
__global__ __launch_bounds__(256) void bcat_kernel(const float* __restrict__ a,
                                                   const float* __restrict__ b,
                                                   float* __restrict__ o) {
    int t = threadIdx.x;
    o[t] = (t < 128) ? a[t] : b[t - 128];
}

// ---------------- SpMM (bf16 gather, row-major in, fragment-major out) ------
// One wave per destination node. Lanes 0-31 (half 0) and 32-63 (half 1) each
// own one edge of a pair; each lane gathers 16B (8 cols). Self-loop + odd tail
// folded into one predicated final iteration. Cross-half shfl_xor reduce.
// Offsets are block-local; the global block prefix bsum[c>>10] is added here
// (scanC eliminated). offsets[n] holds the global total directly.
#define ACC8(qv, uv)                                      \
    do {                                                  \
        float w_ = __uint_as_float((qv).y);               \
        a0 += w_ * __uint_as_float((uv).x << 16);         \
        a1 += w_ * __uint_as_float((uv).x & 0xffff0000u); \
        a2 += w_ * __uint_as_float((uv).y << 16);         \
        a3 += w_ * __uint_as_float((uv).y & 0xffff0000u); \
        a4 += w_ * __uint_as_float((uv).z << 16);         \
        a5 += w_ * __uint_as_float((uv).z & 0xffff0000u); \
        a6 += w_ * __uint_as_float((uv).w << 16);         \
        a7 += w_ * __uint_as_float((uv).w & 0xffff0000u); \
    } while (0)

__global__ __launch_bounds__(256) void spmm_kernel(const unsigned short* __restrict__ h,
                                                   const uint2* __restrict__ edges,
                                                   const int* __restrict__ offsets,
                                                   const int* __restrict__ bsum,
                                                   const float* __restrict__ dinv,
                                                   unsigned short* __restrict__ outf, int n) {
    int wave = threadIdx.x >> 6;
    int lane = threadIdx.x & 63;
    int half = lane >> 5, hl = lane & 31;
    int c = blockIdx.x * 4 + wave;
    if (c >= n) return;
    const uint4* __restrict__ h4 = (const uint4*)h;
    float di = dinv[c];
    int beg = __builtin_amdgcn_readfirstlane(offsets[c] + bsum[c >> 10]);
    int endr;
    if (c + 1 < n) endr = offsets[c + 1] + bsum[(c + 1) >> 10];
    else           endr = offsets[n];  // global total (scanB)
    int end = __builtin_amdgcn_readfirstlane(endr);
    int d = end - beg;
    int elim = beg + (d & ~1);

    float a0 = 0.f, a1 = 0.f, a2 = 0.f, a3 = 0.f;
    float a4 = 0.f, a5 = 0.f, a6 = 0.f, a7 = 0.f;

    int e = beg;
    for (; e + 8 <= elim; e += 8) {
        uint2 q0 = edges[e + 0 + half];
        uint2 q1 = edges[e + 2 + half];
        uint2 q2 = edges[e + 4 + half];
        uint2 q3 = edges[e + 6 + half];
        uint4 u0 = h4[(size_t)q0.x * 32 + hl];
        uint4 u1 = h4[(size_t)q1.x * 32 + hl];
        uint4 u2 = h4[(size_t)q2.x * 32 + hl];
        uint4 u3 = h4[(size_t)q3.x * 32 + hl];
        ACC8(q0, u0);
        ACC8(q1, u1);
        ACC8(q2, u2);
        ACC8(q3, u3);
    }
    for (; e < elim; e += 2) {
        uint2 q = edges[e + half];
        uint4 u = h4[(size_t)q.x * 32 + hl];
        ACC8(q, u);
    }
    // Final iteration: half 0 processes the self-loop (weight dinv[c]; the
    // trailing *di below makes it dinv^2 as required); half 1 processes the
    // odd tail edge if present, else contributes weight 0.
    {
        uint2 qf;
        qf.x = (unsigned int)c;
        qf.y = half ? 0u : __float_as_uint(di);
        if (half && (d & 1)) qf = edges[end - 1];
        uint4 uf = h4[(size_t)qf.x * 32 + hl];
        ACC8(qf, uf);
    }

    // combine halves (both halves cover the same 8 columns)
    a0 += __shfl_xor(a0, 32);
    a1 += __shfl_xor(a1, 32);
    a2 += __shfl_xor(a2, 32);
    a3 += __shfl_xor(a3, 32);
    a4 += __shfl_xor(a4, 32);
    a5 += __shfl_xor(a5, 32);
    a6 += __shfl_xor(a6, 32);
    a7 += __shfl_xor(a7, 32);

    if (half == 0) {
        uint4 wv;
        wv.x = f2bf(di * a0) | (f2bf(di * a1) << 16);
        wv.y = f2bf(di * a2) | (f2bf(di * a3) << 16);
        wv.z = f2bf(di * a4) | (f2bf(di * a5) << 16);
        wv.w = f2bf(di * a6) | (f2bf(di * a7) << 16);
        int T = c >> 4, l = c & 15;
        // lane hl covers cols 8*hl..8*hl+7: K=hl>>2, q=hl&3, j=0..7 contiguous
        size_t o16 = ((size_t)T * 8 + (hl >> 2)) * 512 + (size_t)(hl & 3) * 128 + (size_t)l * 8;
        *(uint4*)(outf + o16) = wv;
    }
}

// ---------------- GEMM body (double-buffered 2-phase), shared by both -------
// flags: 1 = relu, 2 = bf16 output, 4 = dual fp32 output.
static __device__ __forceinline__ void gemm_body(const unsigned short* __restrict__ Af,
                                                 const unsigned short* __restrict__ Wh,
                                                 const unsigned short* __restrict__ Wl,
                                                 const float* __restrict__ bias,
                                                 void* __restrict__ outp,
                                                 int n, int M, int flags,
                                                 int bx, int by, short* lds /*[2][12288]*/) {
    int tid = threadIdx.x, lane = tid & 63, wave = tid >> 6;
    int wr = wave & 1, wc = wave >> 1;
    int l16 = lane & 15, quad = lane >> 4;
    int T0 = bx * 8;   // A tile base (rows /16)
    int Tc0 = by * 8;  // B tile base (cols /16)

    f32x4 acc[4][4];
#pragma unroll
    for (int i = 0; i < 4; ++i)
#pragma unroll
        for (int j = 0; j < 4; ++j) acc[i][j] = (f32x4)0.0f;

    auto stage = [&](int b, int K) {
#pragma unroll
        for (int j = 0; j < 6; ++j) {
            int cid = wave * 6 + j;
            const unsigned short* g;
            if (cid < 8)       g = Af + ((size_t)(T0 + cid) * 8 + K) * 512;
            else if (cid < 16) g = Wh + ((size_t)(Tc0 + cid - 8) * 8 + K) * 512;
            else               g = Wl + ((size_t)(Tc0 + cid - 16) * 8 + K) * 512;
            load_lds16(g + (size_t)lane * 8, lds + b * 12288 + cid * 512);
        }
    };

    stage(0, 0);
    __syncthreads();  // drains vmcnt(0) + barrier: buf0 ready

    for (int K = 0; K < 8; ++K) {
        int cur = K & 1;
        if (K < 7) stage(cur ^ 1, K + 1);  // in flight during compute below
        bf16x8 af[4], bh[4], bl[4];
#pragma unroll
        for (int t = 0; t < 4; ++t) {
            af[t] = *(const bf16x8*)(lds + cur * 12288 + (4 * wr + t) * 512 + lane * 8);
            bh[t] = *(const bf16x8*)(lds + cur * 12288 + 4096 + (4 * wc + t) * 512 + lane * 8);
            bl[t] = *(const bf16x8*)(lds + cur * 12288 + 8192 + (4 * wc + t) * 512 + lane * 8);
        }
#pragma unroll
        for (int rt = 0; rt < 4; ++rt)
#pragma unroll
            for (int ct = 0; ct < 4; ++ct) {
                acc[rt][ct] = __builtin_amdgcn_mfma_f32_16x16x32_bf16(af[rt], bh[ct], acc[rt][ct], 0, 0, 0);
                acc[rt][ct] = __builtin_amdgcn_mfma_f32_16x16x32_bf16(af[rt], bl[ct], acc[rt][ct], 0, 0, 0);
            }
        if (K < 7) __syncthreads();  // drains next-stage vmcnt; buf swap safe
    }

    int relu = flags & 1, obf = flags & 2, dual = flags & 4;
    int r0 = T0 * 16, c0 = Tc0 * 16;
#pragma unroll
    for (int ct = 0; ct < 4; ++ct) {
        int col = c0 + 64 * wc + 16 * ct + l16;
        float b = bias[col];
#pragma unroll
        for (int rt = 0; rt < 4; ++rt) {
            int rbase = r0 + 64 * wr + 16 * rt + quad * 4;
#pragma unroll
            for (int i = 0; i < 4; ++i) {
                int r = rbase + i;
                if (r < n) {
                    float v = acc[rt][ct][i] + b;
                    if (relu) v = fmaxf(v, 0.0f);
                    if (dual)
                        ((float*)outp)[(size_t)(col >> 7) * ((size_t)n * 128) + (size_t)r * 128 + (col & 127)] = v;
                    else if (obf)
                        ((unsigned short*)outp)[(size_t)r * M + col] = (unsigned short)f2bf(v);
                    else
                        ((float*)outp)[(size_t)r * M + col] = v;
                }
            }
        }
    }
}

// Standalone GEMM (GEMM-2 enc, GEMM-3 dual).
__global__ __launch_bounds__(256) void mfma_gemm_kernel(const unsigned short* __restrict__ Af,
                                                        const unsigned short* __restrict__ Wh,
                                                        const unsigned short* __restrict__ Wl,
                                                        const float* __restrict__ bias,
                                                        void* __restrict__ outp,
                                                        int n, int M, int flags) {
    __shared__ short lds[2 * 12288];
    gemm_body(Af, Wh, Wl, bias, outp, n, M, flags, blockIdx.x, blockIdx.y, lds);
}

// Fused GEMM-1 + edge_pack: blocks [0, nGemm) run the dense GEMM (flattened
// bx = b % nTile, by = b / nTile); blocks [nGemm, ...) run edge_pack
// (1 edge/thread; R11's unroll x4 measured slower — queue-depth-insensitive).
__global__ __launch_bounds__(256) void gemm_pack_kernel(const unsigned short* __restrict__ Af,
                                                        const unsigned short* __restrict__ Wh,
                                                        const unsigned short* __restrict__ Wl,
                                                        const float* __restrict__ bias,
                                                        void* __restrict__ outp,
                                                        int n, int M, int flags,
                                                        int nGemm, int nTile,
                                                        const int* __restrict__ col,
                                                        const float* __restrict__ ew,
                                                        unsigned long long* __restrict__ acc,
                                                        unsigned int* __restrict__ rank, int E) {
    __shared__ short lds[2 * 12288];
    int b = blockIdx.x;
    if (b < nGemm) {
        gemm_body(Af, Wh, Wl, bias, outp, n, M, flags, b % nTile, b / nTile, lds);
    } else {
        int e = (b - nGemm) * 256 + threadIdx.x;
        if (e < E) {
            int c = col[e];
            unsigned long long pk = (1ull << 32) |
                                    (unsigned long long)(unsigned int)(ew[e] * FIXSCALE + 0.5f);
            unsigned long long old = atomicAdd(&acc[c], pk);
            rank[e] = (unsigned int)(old >> 32);
        }
    }
}

// ---------------- launch ----------------

extern "C" void kernel_launch(void* const* d_in, const int* in_sizes, int n_in,
                              void* d_out, int out_size, void* d_ws, size_t ws_size,
                              hipStream_t stream) {
    const float* x        = (const float*)d_in[0];
    const int*   ei       = (const int*)d_in[1];   // int32 (harness converts)
    const float* ea       = (const float*)d_in[2];
    const float* w_dense  = (const float*)d_in[3];
    const float* b_dense  = (const float*)d_in[4];
    const float* w_enc    = (const float*)d_in[5];
    const float* b_enc    = (const float*)d_in[6];
    const float* w_mu     = (const float*)d_in[7];
    const float* b_mu     = (const float*)d_in[8];
    const float* w_logstd = (const float*)d_in[9];
    const float* b_logstd = (const float*)d_in[10];

    const int n = in_sizes[0] / 256;  // 100000 (divisible by 16)
    const int E = in_sizes[2];        // 1600000
    const int* row = ei;
    const int* col = ei + E;

    char* ws = (char*)d_ws;
    size_t off = 0;
    auto alloc = [&](size_t bytes) -> void* {
        void* p = ws + off;
        off = (off + bytes + 255) & ~(size_t)255;
        return p;
    };
    const int nTile = (n + 127) / 128;        // 782 row-blocks
    const int nTpad = nTile * 8;              // 6256 T-chunks (pad: garbage ok, never stored)
    unsigned long long* acc = (unsigned long long*)alloc((size_t)n * 8);
    float* dinv   = (float*)alloc((size_t)n * 4);
    int*   offs   = (int*)alloc((size_t)(n + 1) * 4);
    int*   bsum   = (int*)alloc(128 * 4);
    unsigned int* rank = (unsigned int*)alloc((size_t)E * 4);
    uint2* edges  = (uint2*)alloc((size_t)E * 8);
    unsigned short* Af   = (unsigned short*)alloc((size_t)nTpad * 8192);  // frag activations
    unsigned short* wd_h = (unsigned short*)alloc(256 * 256 * 2);
    unsigned short* wd_l = (unsigned short*)alloc(256 * 256 * 2);
    unsigned short* we_h = (unsigned short*)alloc(256 * 256 * 2);
    unsigned short* we_l = (unsigned short*)alloc(256 * 256 * 2);
    unsigned short* wf_h = (unsigned short*)alloc(256 * 256 * 2);  // mu|logstd concat
    unsigned short* wf_l = (unsigned short*)alloc(256 * 256 * 2);
    float*          bcat = (float*)alloc(256 * 4);
    (void)ws_size;

    // d_out doubles as row-major activation storage (dead before final writes)
    unsigned short* h1b = (unsigned short*)d_out;                    // lower: h1, then mu
    unsigned short* h0b = (unsigned short*)d_out + (size_t)n * 256;  // upper: h0, then logstd

    int nb_n = (n + 255) / 256;
    int nb_e = (E + 255) / 256;
    int nb_s = (n + 1023) / 1024;  // 98 scan blocks
    int nGemm = nTile * 2;         // 1564 GEMM blocks in the fused dispatch

    // prep (independent of edges)
    hipMemsetAsync(acc, 0, (size_t)n * 8, stream);
    cvt_frag_kernel<<<(n * 64 + 255) / 256, 256, 0, stream>>>(x, Af, n);
    splitw_kernel<<<256, 256, 0, stream>>>(w_dense, 256, wd_h, wd_l);
    splitw_kernel<<<256, 256, 0, stream>>>(w_enc, 256, we_h, we_l);
    splitw_kernel<<<128, 256, 0, stream>>>(w_mu, 128, wf_h, wf_l);
    splitw_kernel<<<128, 256, 0, stream>>>(w_logstd, 128, wf_h + 32768, wf_l + 32768);
    bcat_kernel<<<1, 256, 0, stream>>>(b_mu, b_logstd, bcat);

    // fused: GEMM-1 (dense+relu, bf16 out) overlapped with edge_pack atomics
    gemm_pack_kernel<<<nGemm + nb_e, 256, 0, stream>>>(Af, wd_h, wd_l, b_dense, h0b,
                                                       n, 256, 1 | 2, nGemm, nTile,
                                                       col, ea, acc, rank, E);

    // rest of graph preprocessing (dinv fused into scanA; scanC eliminated)
    scanA_kernel<<<nb_s, 1024, 0, stream>>>(acc, offs, bsum, dinv, n);
    scanB_kernel<<<1, 128, 0, stream>>>(bsum, nb_s, offs, n);
    fill2_kernel<<<nb_e, 256, 0, stream>>>(row, col, ea, rank, offs, bsum, dinv, edges, E);

    // pipeline
    spmm_kernel<<<(n + 3) / 4, 256, 0, stream>>>(h0b, edges, offs, bsum, dinv, Af, n);
    mfma_gemm_kernel<<<dim3(nTile, 2), 256, 0, stream>>>(Af, we_h, we_l, b_enc, h1b, n, 256, 2);
    spmm_kernel<<<(n + 3) / 4, 256, 0, stream>>>(h1b, edges, offs, bsum, dinv, Af, n);
    mfma_gemm_kernel<<<dim3(nTile, 2), 256, 0, stream>>>(Af, wf_h, wf_l, bcat, d_out, n, 128, 4);
}